// Round 10
// baseline (144.416 us; speedup 1.0000x reference)
//
#include <hip/hip_runtime.h>

#define IN_H  224
#define IN_W  224
#define OUT_H 218
#define OUT_W 218
#define NCH   64
#define PLANE (OUT_H * OUT_W)
#define TSTR  232            // input tile row stride (floats)
#define NROW  4              // output rows per block
#define NYB   55             // ceil(218/4)
#define NHF   8              // channel half-groups of 8
#define OCH   876            // obuf per-plane chunk stride (872 data + 4 pad)
#define NBLK  (32 * NHF * NYB)   // 14080 = 8 XCDs * 1760 -> bijective chunk map

typedef short bf16x8 __attribute__((ext_vector_type(8)));
typedef float f32x4  __attribute__((ext_vector_type(4)));

__device__ inline unsigned int f2bf(float f) {   // RNE f32 -> bf16 (proven R5-R9)
    unsigned int u = __builtin_bit_cast(unsigned int, f);
    return (u + 0x7fffu + ((u >> 16) & 1u)) >> 16;
}

// Pack weights into MFMA A-fragments (bf16, 7x7 zero-padded to 8x8). Verified R5-R9.
// [fc = mt*2+kt][lane]: ch = 16*mt + (lane&15), dy = 4*kt + (lane>>4),
// word j = {dx=2j (lo), dx=2j+1 (hi)}.
__global__ __launch_bounds__(512) void repack_w(const float* __restrict__ wgt,
                                                unsigned int* __restrict__ wa) {
    const int t    = threadIdx.x;
    const int lane = t & 63;
    const int fc   = t >> 6;
    const int mt   = fc >> 1, kt = fc & 1;
    const int ch   = 16 * mt + (lane & 15);
    const int dy   = 4 * kt + (lane >> 4);
    unsigned int w[4];
#pragma unroll
    for (int j = 0; j < 4; ++j) {
        float lo = (dy < 7 && 2 * j     < 7) ? wgt[ch * 49 + dy * 7 + 2 * j]     : 0.f;
        float hi = (dy < 7 && 2 * j + 1 < 7) ? wgt[ch * 49 + dy * 7 + 2 * j + 1] : 0.f;
        w[j] = f2bf(lo) | (f2bf(hi) << 16);
    }
    reinterpret_cast<uint4*>(wa)[fc * 64 + lane] = make_uint4(w[0], w[1], w[2], w[3]);
}

// Block = (image n, 8-channel half-group h, 4 consecutive rows y0..y0+3),
// 256 threads / 4 waves, 37.3KB LDS -> 4 blocks/CU resident. The MFMA
// computes the full 16-row m-tile (mt=h>>1); the block stores only its 8
// planes as 3488B contiguous dwordx4 runs (R9's proven store). 4 resident
// blocks keep HBM store queues fed while others compute (R10 overlap theory).
__global__ __launch_bounds__(256) void conv7x7_row(
    const float* __restrict__ in,
    const unsigned int* __restrict__ wa,
    float* __restrict__ out)
{
    __shared__ float tile[10 * TSTR];     // 9280 B: input rows y0..y0+9 (+zero pad)
    __shared__ float obuf[8 * OCH];       // 28032 B: 8 planes x (4 rows x 218)

    const int tid  = threadIdx.x;
    const int lane = tid & 63;
    const int wid  = tid >> 6;            // 0..3
    const int g    = lane >> 4;           // k-group -> dy / C-row group
    const int c    = lane & 15;           // pixel-in-group

    // Chunked XCD map (bijective: 14080 = 8*1760): XCD k gets 4 whole images,
    // y innermost -> adjacent ranks extend the same planes' runs.
    const int bid  = blockIdx.x;
    const int rank = (bid & 7) * (NBLK / 8) + (bid >> 3);
    const int n    = rank / (NHF * NYB);
    const int rem  = rank - n * (NHF * NYB);
    const int h    = rem / NYB;           // 8-channel half-group
    const int yb   = rem - h * NYB;
    const int y0   = yb * NROW;           // <= 216
    const int mt   = h >> 1;              // 16-ch m-tile containing this half
    const int hl   = h & 1;               // low/high 8 rows of the m-tile

    // ---- stationary A-fragments for this m-tile ----
    union AB { uint4 u; bf16x8 v; };
    AB af[2];
    const uint4* wa4 = reinterpret_cast<const uint4*>(wa);
#pragma unroll
    for (int kt = 0; kt < 2; ++kt) af[kt].u = wa4[(mt * 2 + kt) * 64 + lane];

    // ---- stage 10 input rows (clamped at bottom; clamped rows feed only
    //      outputs y>=218 which are never stored) ----
    const float* inb = in + (size_t)n * (IN_H * IN_W);
    for (int idx = tid; idx < 10 * 116; idx += 256) {
        int r = idx / 116, c2 = idx - r * 116;
        int iny = min(y0 + r, IN_H - 1);
        float2 v = (c2 < 112) ? *reinterpret_cast<const float2*>(inb + iny * IN_W + 2 * c2)
                              : make_float2(0.f, 0.f);   // zero pad cols 224..231
        tile[r * TSTR + 2 * c2]     = v.x;
        tile[r * TSTR + 2 * c2 + 1] = v.y;
    }
    __syncthreads();

    // ---- compute: 56 (row r, strip s) pairs over 4 waves = 14 each ----
    for (int k = wid; k < 4 * 14; k += 4) {
        const int r  = k / 14;
        const int x0 = 16 * (k - 14 * r);

        AB bf[2];
#pragma unroll
        for (int kt = 0; kt < 2; ++kt) {
            // row r+4kt+g; index 10 (r=3,kt=1,g=3) meets only zero weights ->
            // clamp to 9 (finite data x 0 = 0).
            const int row = min(r + 4 * kt + g, 9);
            const float* rb = &tile[row * TSTR + x0 + c];
            unsigned int b0 = f2bf(rb[0]) | (f2bf(rb[1]) << 16);
            unsigned int b1 = f2bf(rb[2]) | (f2bf(rb[3]) << 16);
            unsigned int b2 = f2bf(rb[4]) | (f2bf(rb[5]) << 16);
            unsigned int b3 = f2bf(rb[6]) | (f2bf(rb[7]) << 16);
            bf[kt].u = make_uint4(b0, b1, b2, b3);
        }

        f32x4 acc = {0.f, 0.f, 0.f, 0.f};
        acc = __builtin_amdgcn_mfma_f32_16x16x32_bf16(af[0].v, bf[0].v, acc, 0, 0, 0);
        acc = __builtin_amdgcn_mfma_f32_16x16x32_bf16(af[1].v, bf[1].v, acc, 0, 0, 0);

        // Keep only C-rows in this half: rows 4g+rr with g in {2hl, 2hl+1}.
        // Plane-in-half p = 4*(g&1)+rr. Mask col>=218 (no pad).
        if ((g >> 1) == hl && x0 + c < OUT_W) {
#pragma unroll
            for (int rr = 0; rr < 4; ++rr)
                obuf[(4 * (g & 1) + rr) * OCH + r * OUT_W + x0 + c] = acc[rr];
        }
    }
    __syncthreads();

    // ---- store: wave w -> planes 2w,2w+1; each plane one 3488B contiguous
    //      16B-aligned run = 218 dwordx4 (109 for the 2-row tail block) ----
    const int vrows = min(NROW, OUT_H - y0);
    const int nf4   = (vrows * OUT_W) >> 2;        // 218 or 109
    const size_t base = ((size_t)(n * NCH + 8 * h)) * PLANE + (size_t)y0 * OUT_W;
#pragma unroll
    for (int i = 0; i < 2; ++i) {
        const int p = 2 * wid + i;
        const float* src = &obuf[p * OCH];
        float* dst = out + base + (size_t)p * PLANE;
#pragma unroll
        for (int j = 0; j < 4; ++j) {
            int idx = 64 * j + lane;
            if (idx < nf4)
                *reinterpret_cast<float4*>(dst + 4 * idx) =
                    *reinterpret_cast<const float4*>(src + 4 * idx);
        }
    }
}

extern "C" void kernel_launch(void* const* d_in, const int* in_sizes, int n_in,
                              void* d_out, int out_size, void* d_ws, size_t ws_size,
                              hipStream_t stream) {
    const float* in  = (const float*)d_in[0];
    const float* wgt = (const float*)d_in[1];
    float* out = (float*)d_out;
    unsigned int* wa = (unsigned int*)d_ws;   // 8*64*16 = 8192 B

    repack_w<<<1, 512, 0, stream>>>(wgt, wa);
    conv7x7_row<<<NBLK, 256, 0, stream>>>(in, wa, out);
}

// Round 12
// 89.098 us; speedup vs baseline: 1.6209x; 1.6209x over previous
//
#include <hip/hip_runtime.h>
#include <hip/hip_bf16.h>

#define IN_H  224
#define IN_W  224
#define OUT_H 218
#define OUT_W 218
#define NCH   64
#define PLANE (OUT_H * OUT_W)
#define TSTR  232            // input tile row stride (floats)
#define NROW  4              // output rows per block
#define NYB   55             // ceil(218/4)
#define NMT   4              // channel groups of 16
#define OCH   876            // obuf per-plane chunk stride (872 data + 4 pad)
#define NBLK  (32 * NMT * NYB)   // 7040 = 8 XCDs * 880 -> bijective chunk map

typedef short bf16x8 __attribute__((ext_vector_type(8)));
typedef float f32x4  __attribute__((ext_vector_type(4)));

__device__ inline unsigned int f2bf(float f) {   // RNE f32 -> bf16 (cold path)
    unsigned int u = __builtin_bit_cast(unsigned int, f);
    return (u + 0x7fffu + ((u >> 16) & 1u)) >> 16;
}

// Pack weights into MFMA A-fragments (bf16, 7x7 zero-padded to 8x8). Verified R5-R10.
// [fc = mt*2+kt][lane]: ch = 16*mt + (lane&15), dy = 4*kt + (lane>>4),
// word j = {dx=2j (lo), dx=2j+1 (hi)}.
__global__ __launch_bounds__(512) void repack_w(const float* __restrict__ wgt,
                                                unsigned int* __restrict__ wa) {
    const int t    = threadIdx.x;
    const int lane = t & 63;
    const int fc   = t >> 6;
    const int mt   = fc >> 1, kt = fc & 1;
    const int ch   = 16 * mt + (lane & 15);
    const int dy   = 4 * kt + (lane >> 4);
    unsigned int w[4];
#pragma unroll
    for (int j = 0; j < 4; ++j) {
        float lo = (dy < 7 && 2 * j     < 7) ? wgt[ch * 49 + dy * 7 + 2 * j]     : 0.f;
        float hi = (dy < 7 && 2 * j + 1 < 7) ? wgt[ch * 49 + dy * 7 + 2 * j + 1] : 0.f;
        w[j] = f2bf(lo) | (f2bf(hi) << 16);
    }
    reinterpret_cast<uint4*>(wa)[fc * 64 + lane] = make_uint4(w[0], w[1], w[2], w[3]);
}

// R9 structure (proven 93.9us): block = (n, mt, 4 rows), 512 thr, 2 blocks/CU,
// 3488B contiguous dwordx4 store runs, y-innermost chunked XCD map.
// R12 change (= R11 intent): B-build uses native paired bf16 converts
// (v_cvt_pk_bf16_f32 via __float22bfloat162_rn) instead of ~8-op bit-twiddle
// per word -> cuts the compute phase that serializes with store drain.
// (bit_cast -> memcpy: __hip_bfloat162 is not trivially copyable.)
__global__ __launch_bounds__(512) void conv7x7_row(
    const float* __restrict__ in,
    const unsigned int* __restrict__ wa,
    float* __restrict__ out)
{
    __shared__ float tile[10 * TSTR];     //  9280 B: input rows y0..y0+9 (+zero pad)
    __shared__ float obuf[16 * OCH];      // 56064 B: 16 planes x (4 rows x 218)

    const int tid  = threadIdx.x;
    const int lane = tid & 63;
    const int wid  = tid >> 6;
    const int g    = lane >> 4;           // k-group -> dy / channel sub-row
    const int c    = lane & 15;           // pixel-in-group

    // Chunked XCD map (bijective: 7040 = 8*880): XCD k gets 4 whole images,
    // y-innermost so adjacent ranks extend the same planes' runs.
    const int bid  = blockIdx.x;
    const int rank = (bid & 7) * (NBLK / 8) + (bid >> 3);
    const int n    = rank / (NMT * NYB);
    const int rem  = rank - n * (NMT * NYB);
    const int mt   = rem / NYB;
    const int yb   = rem - mt * NYB;
    const int y0   = yb * NROW;           // <= 216

    // ---- stationary A-fragments for this channel group ----
    union AB { uint4 u; bf16x8 v; };
    AB af[2];
    const uint4* wa4 = reinterpret_cast<const uint4*>(wa);
#pragma unroll
    for (int kt = 0; kt < 2; ++kt) af[kt].u = wa4[(mt * 2 + kt) * 64 + lane];

    // ---- stage 10 input rows (clamped at image bottom; clamped rows feed
    //      only outputs y>=218 which are never stored) ----
    const float* inb = in + (size_t)n * (IN_H * IN_W);
    for (int idx = tid; idx < 10 * 116; idx += 512) {
        int r = idx / 116, c2 = idx - r * 116;
        int iny = min(y0 + r, IN_H - 1);
        float2 v = (c2 < 112) ? *reinterpret_cast<const float2*>(inb + iny * IN_W + 2 * c2)
                              : make_float2(0.f, 0.f);   // zero pad cols 224..231
        tile[r * TSTR + 2 * c2]     = v.x;
        tile[r * TSTR + 2 * c2 + 1] = v.y;
    }
    __syncthreads();

    // ---- compute: 56 (row r, strip s) pairs over 8 waves = 7 each ----
    for (int k = wid; k < 4 * 14; k += 8) {
        const int r  = k / 14;
        const int x0 = 16 * (k - 14 * r);

        AB bf[2];
#pragma unroll
        for (int kt = 0; kt < 2; ++kt) {
            // row r+4kt+g; index 10 (only r=3,kt=1,g=3) carries zero weights ->
            // clamp to 9 (finite data x 0 = 0).
            const int row = min(r + 4 * kt + g, 9);
            const float* rb = &tile[row * TSTR + x0 + c];
            union { unsigned int u[4]; uint4 q; } bb;
#pragma unroll
            for (int j = 0; j < 4; ++j) {
                __hip_bfloat162 h2 =
                    __float22bfloat162_rn(make_float2(rb[2 * j], rb[2 * j + 1]));
                unsigned int uw;
                __builtin_memcpy(&uw, &h2, sizeof(uw));
                bb.u[j] = uw;
            }
            bf[kt].u = bb.q;
        }

        f32x4 acc = {0.f, 0.f, 0.f, 0.f};
        acc = __builtin_amdgcn_mfma_f32_16x16x32_bf16(af[0].v, bf[0].v, acc, 0, 0, 0);
        acc = __builtin_amdgcn_mfma_f32_16x16x32_bf16(af[1].v, bf[1].v, acc, 0, 0, 0);

        // obuf[plane=4g+rr][row r][col]; mask col>=218
        if (x0 + c < OUT_W) {
#pragma unroll
            for (int rr = 0; rr < 4; ++rr)
                obuf[(4 * g + rr) * OCH + r * OUT_W + x0 + c] = acc[rr];
        }
    }
    __syncthreads();

    // ---- store: wave w -> planes 2w,2w+1; each plane one 3488B contiguous
    //      16B-aligned run = 218 dwordx4 (109 for the 2-row tail block) ----
    const int vrows = min(NROW, OUT_H - y0);
    const int nf4   = (vrows * OUT_W) >> 2;        // 218 or 109
    const size_t base = ((size_t)(n * NCH + 16 * mt)) * PLANE + (size_t)y0 * OUT_W;
#pragma unroll
    for (int i = 0; i < 2; ++i) {
        const int p = 2 * wid + i;
        const float* src = &obuf[p * OCH];
        float* dst = out + base + (size_t)p * PLANE;
#pragma unroll
        for (int j = 0; j < 4; ++j) {
            int idx = 64 * j + lane;
            if (idx < nf4)
                *reinterpret_cast<float4*>(dst + 4 * idx) =
                    *reinterpret_cast<const float4*>(src + 4 * idx);
        }
    }
}

extern "C" void kernel_launch(void* const* d_in, const int* in_sizes, int n_in,
                              void* d_out, int out_size, void* d_ws, size_t ws_size,
                              hipStream_t stream) {
    const float* in  = (const float*)d_in[0];
    const float* wgt = (const float*)d_in[1];
    float* out = (float*)d_out;
    unsigned int* wa = (unsigned int*)d_ws;   // 8*64*16 = 8192 B

    repack_w<<<1, 512, 0, stream>>>(wgt, wa);
    conv7x7_row<<<NBLK, 512, 0, stream>>>(in, wa, out);
}